// Round 1
// baseline (114822.766 us; speedup 1.0000x reference)
//
#include <hip/hip_runtime.h>
#include <cmath>

typedef __attribute__((ext_vector_type(4))) float f32x4;
typedef __attribute__((ext_vector_type(8))) short s16x8;
typedef __attribute__((ext_vector_type(4))) short s16x4;

#define TSTEPS 4096

__device__ __forceinline__ short f2bf(float f) {
  unsigned u = __float_as_uint(f);
  unsigned r = (u + 0x7FFFu + ((u >> 16) & 1u)) >> 16;
  return (short)r;
}
__device__ __forceinline__ float bf2f(short s) {
  return __uint_as_float(((unsigned)(unsigned short)s) << 16);
}

// ---------------- pre1[t*8+b][j] = x[b,t,:] @ W1a^T + b1  (fp32) ----------------
__global__ void __launch_bounds__(256) pre_gemm(
    const float* __restrict__ x, const float* __restrict__ W1,
    const float* __restrict__ b1, float* __restrict__ pre1)
{
  __shared__ float As[16][136];
  __shared__ float Bs[16][136];
  const int tid = threadIdx.x;
  const int m0 = blockIdx.x * 128, j0 = blockIdx.y * 128;
  const int r = tid >> 1, half = tid & 1;
  const int tx = tid & 15, ty = tid >> 4;

  float acc[8][8];
#pragma unroll
  for (int a = 0; a < 8; a++)
#pragma unroll
    for (int b = 0; b < 8; b++) acc[a][b] = 0.f;

  const int row = m0 + r;  // row = t*8 + b
  const float* xrow = x + (((size_t)(row & 7) * 4096) + (size_t)(row >> 3)) * 512;
  const float* wrow = W1 + (size_t)(j0 + r) * 1024;  // W1a = cols [0,512)

  for (int k0 = 0; k0 < 512; k0 += 16) {
    f32x4 a0 = *(const f32x4*)(xrow + k0 + half * 8);
    f32x4 a1 = *(const f32x4*)(xrow + k0 + half * 8 + 4);
    f32x4 w0 = *(const f32x4*)(wrow + k0 + half * 8);
    f32x4 w1 = *(const f32x4*)(wrow + k0 + half * 8 + 4);
    __syncthreads();
#pragma unroll
    for (int q = 0; q < 4; q++) {
      As[half * 8 + q][r] = a0[q];
      As[half * 8 + 4 + q][r] = a1[q];
      Bs[half * 8 + q][r] = w0[q];
      Bs[half * 8 + 4 + q][r] = w1[q];
    }
    __syncthreads();
#pragma unroll
    for (int kk = 0; kk < 16; kk++) {
      f32x4 ra0 = *(const f32x4*)&As[kk][ty * 8];
      f32x4 ra1 = *(const f32x4*)&As[kk][ty * 8 + 4];
      f32x4 rb0 = *(const f32x4*)&Bs[kk][tx * 8];
      f32x4 rb1 = *(const f32x4*)&Bs[kk][tx * 8 + 4];
#pragma unroll
      for (int a = 0; a < 4; a++)
#pragma unroll
        for (int b = 0; b < 4; b++) {
          acc[a][b]         += ra0[a] * rb0[b];
          acc[a][b + 4]     += ra0[a] * rb1[b];
          acc[a + 4][b]     += ra1[a] * rb0[b];
          acc[a + 4][b + 4] += ra1[a] * rb1[b];
        }
    }
  }
  float bias[8];
#pragma unroll
  for (int b = 0; b < 8; b++) bias[b] = b1[j0 + tx * 8 + b];
#pragma unroll
  for (int a = 0; a < 8; a++) {
    float* dst = pre1 + (size_t)(m0 + ty * 8 + a) * 1024 + j0 + tx * 8;
    f32x4 v0, v1;
#pragma unroll
    for (int b = 0; b < 4; b++) { v0[b] = acc[a][b] + bias[b]; v1[b] = acc[a][b + 4] + bias[b + 4]; }
    *(f32x4*)dst = v0;
    *(f32x4*)(dst + 4) = v1;
  }
}

// ---------------- persistent sequential scan: 32 worker blocks ----------------
// LDS: W1b hi/lo [32][520] bf16, W2 hi/lo [16][1032] bf16, scratch 1024 f32 = 136704 B
__global__ void __launch_bounds__(256) seq_scan(
    const float* __restrict__ W1, const float* __restrict__ b1,
    const float* __restrict__ W2, const float* __restrict__ b2,
    const float* __restrict__ pre1, float* __restrict__ out,
    float* __restrict__ mem_f32, short* __restrict__ mem_hi,
    short* __restrict__ mem_lo, short* __restrict__ h_hi,
    short* __restrict__ h_lo, unsigned* __restrict__ bar)
{
  if (blockIdx.x & 7) return;        // 32 workers: blocks 0,8,...,248 (one XCD if i%8 mapping)
  const int cu = blockIdx.x >> 3;    // 0..31
  const int tid = threadIdx.x;
  const int lane = tid & 63;
  const int wv = tid >> 6;           // 0..3
  const int mrow = lane & 15;
  const int kgrp = lane >> 4;

  extern __shared__ char lds[];
  short* w1h = (short*)lds;               // [32][520]
  short* w1l = w1h + 32 * 520;
  short* w2h = w1l + 32 * 520;            // [16][1032]
  short* w2l = w2h + 16 * 1032;
  float* scr = (float*)(w2l + 16 * 1032); // 1024 f32

  // ---- preload weights into LDS as bf16 hi/lo splits ----
  for (int e = tid; e < 32 * 128; e += 256) {
    int jl = e >> 7, k4 = (e & 127) << 2;
    f32x4 v = *(const f32x4*)(W1 + (size_t)(cu * 32 + jl) * 1024 + 512 + k4); // W1b
#pragma unroll
    for (int q = 0; q < 4; q++) {
      short hi = f2bf(v[q]);
      w1h[jl * 520 + k4 + q] = hi;
      w1l[jl * 520 + k4 + q] = f2bf(v[q] - bf2f(hi));
    }
  }
  for (int e = tid; e < 16 * 256; e += 256) {
    int il = e >> 8, k4 = (e & 255) << 2;
    f32x4 v = *(const f32x4*)(W2 + (size_t)(cu * 16 + il) * 1024 + k4);
#pragma unroll
    for (int q = 0; q < 4; q++) {
      short hi = f2bf(v[q]);
      w2h[il * 1032 + k4 + q] = hi;
      w2l[il * 1032 + k4 + q] = f2bf(v[q] - bf2f(hi));
    }
  }
  __syncthreads();

  unsigned p = 0;
  const int i0 = cu * 16 + kgrp * 4;

  for (int t = 0; t < TSTEPS; t++) {
    // ---- phase 1: h = gelu(pre1[t] + mem @ W1b^T + b1), our 32 j-columns ----
    if (wv < 2) {
      const int jl0 = wv << 4;
      const int wrow_off = (jl0 + mrow) * 520;
      f32x4 acc0 = {0.f, 0.f, 0.f, 0.f}, acc1 = acc0, acc2 = acc0;
      for (int ks = 0; ks < 16; ks++) {
        const int ko = ks * 32 + kgrp * 8;
        s16x8 ah = *(const s16x8*)(mem_hi + mrow * 512 + ko);
        s16x8 al = *(const s16x8*)(mem_lo + mrow * 512 + ko);
        s16x8 bh = *(const s16x8*)(w1h + wrow_off + ko);
        s16x8 bl = *(const s16x8*)(w1l + wrow_off + ko);
        acc0 = __builtin_amdgcn_mfma_f32_16x16x32_bf16(ah, bh, acc0, 0, 0, 0);
        acc1 = __builtin_amdgcn_mfma_f32_16x16x32_bf16(al, bh, acc1, 0, 0, 0);
        acc2 = __builtin_amdgcn_mfma_f32_16x16x32_bf16(ah, bl, acc2, 0, 0, 0);
      }
      f32x4 acc = acc0 + acc1 + acc2;
      const int jg = cu * 32 + jl0 + mrow;
      const float bias = b1[jg];
#pragma unroll
      for (int rr = 0; rr < 4; rr++) {
        const int m = kgrp * 4 + rr;
        float xv = acc[rr] + pre1[((size_t)t * 8 + (m & 7)) * 1024 + jg] + bias;
        float hv = 0.5f * xv * (1.0f + erff(xv * 0.70710678118654752f));
        if (m < 8) {
          short hh = f2bf(hv);
          h_hi[m * 1024 + jg] = hh;
          h_lo[m * 1024 + jg] = f2bf(hv - bf2f(hh));
        }
      }
    }
    // ---- barrier A ----
    __syncthreads();
    p++;
    if (tid == 0) {
      __threadfence();
      __hip_atomic_fetch_add(bar, 1u, __ATOMIC_RELAXED, __HIP_MEMORY_SCOPE_AGENT);
      while (__hip_atomic_load(bar, __ATOMIC_RELAXED, __HIP_MEMORY_SCOPE_AGENT) < 32u * p) {}
      __threadfence();
    }
    __syncthreads();

    // ---- phase 2: proposed^T = W2 @ h^T (our 16 i-rows), k-split over 4 waves ----
    {
      f32x4 acc0 = {0.f, 0.f, 0.f, 0.f}, acc1 = acc0, acc2 = acc0;
      const int a_off = mrow * 1032;
      const int b_off = mrow * 1024;
      for (int s = 0; s < 8; s++) {
        const int ko = (wv * 8 + s) * 32 + kgrp * 8;
        s16x8 ah = *(const s16x8*)(w2h + a_off + ko);
        s16x8 al = *(const s16x8*)(w2l + a_off + ko);
        s16x8 bh = *(const s16x8*)(h_hi + b_off + ko);
        s16x8 bl = *(const s16x8*)(h_lo + b_off + ko);
        acc0 = __builtin_amdgcn_mfma_f32_16x16x32_bf16(ah, bh, acc0, 0, 0, 0);
        acc1 = __builtin_amdgcn_mfma_f32_16x16x32_bf16(al, bh, acc1, 0, 0, 0);
        acc2 = __builtin_amdgcn_mfma_f32_16x16x32_bf16(ah, bl, acc2, 0, 0, 0);
      }
      f32x4 acc = acc0 + acc1 + acc2;
      *(f32x4*)(scr + (wv * 64 + lane) * 4) = acc;
    }
    __syncthreads();
    if (wv == 0 && mrow < 8) {
      f32x4 s0 = *(const f32x4*)(scr + lane * 4);
      f32x4 s1 = *(const f32x4*)(scr + (64 + lane) * 4);
      f32x4 s2 = *(const f32x4*)(scr + (128 + lane) * 4);
      f32x4 s3 = *(const f32x4*)(scr + (192 + lane) * 4);
      f32x4 pr = s0 + s1 + s2 + s3;
      f32x4 old4 = *(const f32x4*)(mem_f32 + mrow * 512 + i0);
      f32x4 nm4; s16x4 nh4, nl4;
#pragma unroll
      for (int rr = 0; rr < 4; rr++) {
        float prop = pr[rr] + b2[i0 + rr];
        float g = 1.0f / (1.0f + __expf(-prop));
        float nm = old4[rr] + g * (prop - old4[rr]);
        nm4[rr] = nm;
        short hh = f2bf(nm);
        nh4[rr] = hh;
        nl4[rr] = f2bf(nm - bf2f(hh));
      }
      *(f32x4*)(mem_f32 + mrow * 512 + i0) = nm4;
      *(s16x4*)(mem_hi + mrow * 512 + i0) = nh4;
      *(s16x4*)(mem_lo + mrow * 512 + i0) = nl4;
      *(f32x4*)(out + ((size_t)mrow * 4096 + t) * 512 + i0) = nm4;
    }
    // ---- barrier B ----
    __syncthreads();
    p++;
    if (tid == 0) {
      __threadfence();
      __hip_atomic_fetch_add(bar, 1u, __ATOMIC_RELAXED, __HIP_MEMORY_SCOPE_AGENT);
      while (__hip_atomic_load(bar, __ATOMIC_RELAXED, __HIP_MEMORY_SCOPE_AGENT) < 32u * p) {}
      __threadfence();
    }
    __syncthreads();
  }
}

extern "C" void kernel_launch(void* const* d_in, const int* in_sizes, int n_in,
                              void* d_out, int out_size, void* d_ws, size_t ws_size,
                              hipStream_t stream) {
  const float* x  = (const float*)d_in[0];
  const float* W1 = (const float*)d_in[1];
  const float* b1 = (const float*)d_in[2];
  const float* W2 = (const float*)d_in[3];
  const float* b2 = (const float*)d_in[4];
  float* out = (float*)d_out;
  char* ws = (char*)d_ws;

  // workspace layout (needs >= 1MB + 134.2MB)
  float*    mem_f32 = (float*)(ws + 0);        // 16*512*4   = 32768
  short*    mem_hi  = (short*)(ws + 32768);    // 16*512*2   = 16384
  short*    mem_lo  = (short*)(ws + 49152);    // 16384
  unsigned* bar     = (unsigned*)(ws + 65536); // 4
  short*    h_hi    = (short*)(ws + 65792);    // 16*1024*2  = 32768
  short*    h_lo    = (short*)(ws + 98560);    // 32768
  float*    pre1    = (float*)(ws + (1u << 20)); // 4096*8*1024*4 = 134217728

  // zero mem state + barrier
  hipMemsetAsync(ws, 0, 65792, stream);

  dim3 gp(256, 8);
  pre_gemm<<<gp, dim3(256), 0, stream>>>(x, W1, b1, pre1);

  const int LDS_BYTES = 136704;
  hipFuncSetAttribute((const void*)seq_scan,
                      hipFuncAttributeMaxDynamicSharedMemorySize, LDS_BYTES);
  seq_scan<<<dim3(256), dim3(256), LDS_BYTES, stream>>>(
      W1, b1, W2, b2, pre1, out, mem_f32, mem_hi, mem_lo, h_hi, h_lo, bar);
}

// Round 2
// 19487.569 us; speedup vs baseline: 5.8921x; 5.8921x over previous
//
#include <hip/hip_runtime.h>
#include <cmath>

typedef __attribute__((ext_vector_type(4))) float f32x4;
typedef __attribute__((ext_vector_type(8))) short s16x8;
typedef __attribute__((ext_vector_type(4))) short s16x4;
typedef unsigned long long u64;

#define TSTEPS 4096
#define NCU 32

__device__ __forceinline__ short f2bf(float f) {
  unsigned u = __float_as_uint(f);
  unsigned r = (u + 0x7FFFu + ((u >> 16) & 1u)) >> 16;
  return (short)r;
}
__device__ __forceinline__ float bf2f(short s) {
  return __uint_as_float(((unsigned)(unsigned short)s) << 16);
}

// ---------------- pre1[t*8+b][j] = x[b,t,:] @ W1a^T + b1  (fp32) ----------------
__global__ void __launch_bounds__(256) pre_gemm(
    const float* __restrict__ x, const float* __restrict__ W1,
    const float* __restrict__ b1, float* __restrict__ pre1)
{
  __shared__ float As[16][136];
  __shared__ float Bs[16][136];
  const int tid = threadIdx.x;
  const int m0 = blockIdx.x * 128, j0 = blockIdx.y * 128;
  const int r = tid >> 1, half = tid & 1;
  const int tx = tid & 15, ty = tid >> 4;

  float acc[8][8];
#pragma unroll
  for (int a = 0; a < 8; a++)
#pragma unroll
    for (int b = 0; b < 8; b++) acc[a][b] = 0.f;

  const int row = m0 + r;  // row = t*8 + b
  const float* xrow = x + (((size_t)(row & 7) * 4096) + (size_t)(row >> 3)) * 512;
  const float* wrow = W1 + (size_t)(j0 + r) * 1024;  // W1a = cols [0,512)

  for (int k0 = 0; k0 < 512; k0 += 16) {
    f32x4 a0 = *(const f32x4*)(xrow + k0 + half * 8);
    f32x4 a1 = *(const f32x4*)(xrow + k0 + half * 8 + 4);
    f32x4 w0 = *(const f32x4*)(wrow + k0 + half * 8);
    f32x4 w1 = *(const f32x4*)(wrow + k0 + half * 8 + 4);
    __syncthreads();
#pragma unroll
    for (int q = 0; q < 4; q++) {
      As[half * 8 + q][r] = a0[q];
      As[half * 8 + 4 + q][r] = a1[q];
      Bs[half * 8 + q][r] = w0[q];
      Bs[half * 8 + 4 + q][r] = w1[q];
    }
    __syncthreads();
#pragma unroll
    for (int kk = 0; kk < 16; kk++) {
      f32x4 ra0 = *(const f32x4*)&As[kk][ty * 8];
      f32x4 ra1 = *(const f32x4*)&As[kk][ty * 8 + 4];
      f32x4 rb0 = *(const f32x4*)&Bs[kk][tx * 8];
      f32x4 rb1 = *(const f32x4*)&Bs[kk][tx * 8 + 4];
#pragma unroll
      for (int a = 0; a < 4; a++)
#pragma unroll
        for (int b = 0; b < 4; b++) {
          acc[a][b]         += ra0[a] * rb0[b];
          acc[a][b + 4]     += ra0[a] * rb1[b];
          acc[a + 4][b]     += ra1[a] * rb0[b];
          acc[a + 4][b + 4] += ra1[a] * rb1[b];
        }
    }
  }
  float bias[8];
#pragma unroll
  for (int b = 0; b < 8; b++) bias[b] = b1[j0 + tx * 8 + b];
#pragma unroll
  for (int a = 0; a < 8; a++) {
    float* dst = pre1 + (size_t)(m0 + ty * 8 + a) * 1024 + j0 + tx * 8;
    f32x4 v0, v1;
#pragma unroll
    for (int b = 0; b < 4; b++) { v0[b] = acc[a][b] + bias[b]; v1[b] = acc[a][b + 4] + bias[b + 4]; }
    *(f32x4*)dst = v0;
    *(f32x4*)(dst + 4) = v1;
  }
}

// ---------------- persistent sequential scan: 32 blocks, j-sliced ----------------
// Per-CU LDS (bytes):
//   w1bh/w1bl : 2 x [32][520] bf16 = 66,560    (W1b rows = our 32 j's, k=0..511)
//   w2h/w2l   : 2 x [512][36] bf16 = 73,728    (W2[i][our 32 j's], stride 36 -> 2x ds_read_b64)
//   memh/meml : 2 x [9][520]  bf16 = 18,720    (rows 0..7 = mem, row 8 = zeros for MFMA pad)
//   hh/hl     : 2 x [9][40]   bf16 =  1,440    (local h slice, row 8 = zeros)
//   scr       : 512 f32            =  2,048    (phase-1 cross-wave k-reduce)
//   total 162,496 <= 163,840
__global__ void __launch_bounds__(256) seq_scan(
    const float* __restrict__ W1, const float* __restrict__ W2,
    const float* __restrict__ b2, const float* __restrict__ pre1,
    float* __restrict__ out, float* __restrict__ accbuf,
    unsigned* __restrict__ bar, unsigned* __restrict__ rel)
{
  const int c = blockIdx.x;          // 0..31, owns j in [32c, 32c+32)
  const int tid = threadIdx.x;
  const int l = tid & 63;
  const int w = tid >> 6;            // wave 0..3

  extern __shared__ char lds[];
  short* w1bh = (short*)lds;                 // [32][520]
  short* w1bl = w1bh + 32 * 520;
  short* w2h  = w1bl + 32 * 520;             // [512][36]
  short* w2l  = w2h + 512 * 36;
  short* memh = w2l + 512 * 36;              // [9][520]
  short* meml = memh + 9 * 520;
  short* hh   = meml + 9 * 520;              // [9][40]
  short* hl   = hh + 9 * 40;
  float* scr  = (float*)(hl + 9 * 40);       // 512 f32

  // ---- preload weight slices into LDS as bf16 hi/lo splits ----
  for (int e = tid; e < 32 * 128; e += 256) {       // W1b: 32 rows x 512 k
    int jl = e >> 7, k4 = (e & 127) << 2;
    f32x4 v = *(const f32x4*)(W1 + (size_t)(c * 32 + jl) * 1024 + 512 + k4);
#pragma unroll
    for (int q = 0; q < 4; q++) {
      short hi = f2bf(v[q]);
      w1bh[jl * 520 + k4 + q] = hi;
      w1bl[jl * 520 + k4 + q] = f2bf(v[q] - bf2f(hi));
    }
  }
  for (int e = tid; e < 512 * 8; e += 256) {        // W2 slice: 512 rows x 32 j
    int i = e >> 3, j4 = (e & 7) << 2;
    f32x4 v = *(const f32x4*)(W2 + (size_t)i * 1024 + c * 32 + j4);
#pragma unroll
    for (int q = 0; q < 4; q++) {
      short hi = f2bf(v[q]);
      w2h[i * 36 + j4 + q] = hi;
      w2l[i * 36 + j4 + q] = f2bf(v[q] - bf2f(hi));
    }
  }
  for (int e = tid; e < 9 * 520; e += 256) { memh[e] = 0; meml[e] = 0; }
  for (int e = tid; e < 9 * 40; e += 256)  { hh[e] = 0; hl[e] = 0; }

  // per-thread state for the gate phase: this thread owns (m = tid>>5, i = (tid&31)*16 + q)
  const int mg = tid >> 5;
  const int i0own = (tid & 31) * 16;
  float memr[16];
  float b2r[16];
#pragma unroll
  for (int q = 0; q < 16; q++) { memr[q] = 0.f; b2r[q] = b2[i0own + q]; }

  // phase-1 epilogue threads: waves 0,1 lanes 0..31 own (m = (l>>4)*4+rr, jg)
  const int jt = w & 1, kh = w >> 1;
  const int jg = c * 32 + jt * 16 + (l & 15);
  const int m_ep = (l >> 4) * 4;
  const bool ep = (w < 2) && (l < 32);
  float p1r[4];
  if (ep) {
#pragma unroll
    for (int rr = 0; rr < 4; rr++) p1r[rr] = pre1[(size_t)(0 * 8 + m_ep + rr) * 1024 + jg];
  }

  const int arow = ((l & 15) < 8) ? (l & 15) : 8;   // clamp pad rows to zero row
  const int aoff = arow * 520 + (l >> 4) * 8;
  const int boff = (jt * 16 + (l & 15)) * 520 + (l >> 4) * 8;
  const int haoff = arow * 40 + (l >> 4) * 8;

  __syncthreads();

  for (int t = 0; t < TSTEPS; t++) {
    // ===== phase 1: h[:, our 32 j] = gelu(pre1 + mem @ W1b^T) =====
    {
      f32x4 a0 = {0.f,0.f,0.f,0.f}, a1 = a0, a2 = a0;
#pragma unroll
      for (int ks = 0; ks < 8; ks++) {
        const int ko = kh * 256 + ks * 32;
        s16x8 ah = *(const s16x8*)(memh + aoff + ko);
        s16x8 al = *(const s16x8*)(meml + aoff + ko);
        s16x8 bh = *(const s16x8*)(w1bh + boff + ko);
        s16x8 bl = *(const s16x8*)(w1bl + boff + ko);
        a0 = __builtin_amdgcn_mfma_f32_16x16x32_bf16(ah, bh, a0, 0, 0, 0);
        a1 = __builtin_amdgcn_mfma_f32_16x16x32_bf16(al, bh, a1, 0, 0, 0);
        a2 = __builtin_amdgcn_mfma_f32_16x16x32_bf16(ah, bl, a2, 0, 0, 0);
      }
      f32x4 acc = a0 + a1 + a2;
      if (w >= 2) *(f32x4*)(scr + (w - 2) * 256 + l * 4) = acc;
      __syncthreads();
      if (w < 2) {
        acc += *(const f32x4*)(scr + w * 256 + l * 4);
        if (l < 32) {
#pragma unroll
          for (int rr = 0; rr < 4; rr++) {
            float xv = acc[rr] + p1r[rr];
            float hv = 0.5f * xv * (1.0f + erff(xv * 0.70710678118654752f));
            short hhi = f2bf(hv);
            hh[(m_ep + rr) * 40 + jt * 16 + (l & 15)] = hhi;
            hl[(m_ep + rr) * 40 + jt * 16 + (l & 15)] = f2bf(hv - bf2f(hhi));
          }
        }
      }
    }
    __syncthreads();

    // ===== phase 2: partial[m,i] += h_slice @ W2_slice^T, atomicAdd into IC =====
    {
      float* accw = accbuf + (size_t)(t & 3) * 4096;
      s16x8 ha = *(const s16x8*)(hh + haoff);
      s16x8 hb = *(const s16x8*)(hl + haoff);
      const int n0 = w * 128;
#pragma unroll
      for (int tt = 0; tt < 8; tt++) {
        const int tl = (tt + c) & 7;                 // rotate tile order per CU
        const int icol = n0 + tl * 16 + (l & 15);
        const int woff = icol * 36 + (l >> 4) * 8;
        s16x8 bh, bl;
        *(s16x4*)&bh = *(const s16x4*)(w2h + woff);
        *((s16x4*)&bh + 1) = *(const s16x4*)(w2h + woff + 4);
        *(s16x4*)&bl = *(const s16x4*)(w2l + woff);
        *((s16x4*)&bl + 1) = *(const s16x4*)(w2l + woff + 4);
        f32x4 p0 = {0.f,0.f,0.f,0.f}, p1 = p0, p2 = p0;
        p0 = __builtin_amdgcn_mfma_f32_16x16x32_bf16(ha, bh, p0, 0, 0, 0);
        p1 = __builtin_amdgcn_mfma_f32_16x16x32_bf16(hb, bh, p1, 0, 0, 0);
        p2 = __builtin_amdgcn_mfma_f32_16x16x32_bf16(ha, bl, p2, 0, 0, 0);
        f32x4 p = p0 + p1 + p2;
        if (l < 32) {
          const int mrow = (l >> 4) * 4;
#pragma unroll
          for (int rr = 0; rr < 4; rr++)
            atomicAdd(accw + ((mrow + rr) << 9) + icol, p[rr]);
        }
      }
    }

    // zero the buffer that will be written at step t+2 (read finished at t-2; safe per mod-4 analysis)
    if (tid < 64) {
      u64* z = (u64*)(accbuf + (size_t)((t + 2) & 3) * 4096);
      __hip_atomic_store(z + c * 64 + tid, 0ull, __ATOMIC_RELAXED, __HIP_MEMORY_SCOPE_AGENT);
    }

    // prefetch pre1 for t+1 (latency hides under the barrier)
    if (ep && t + 1 < TSTEPS) {
#pragma unroll
      for (int rr = 0; rr < 4; rr++)
        p1r[rr] = pre1[(size_t)((t + 1) * 8 + m_ep + rr) * 1024 + jg];
    }

    // ===== global barrier (no cache fences: all shared data moved via device-scope ops) =====
    __syncthreads();   // compiler drains vmcnt(0) here -> atomics complete before arrival
    if (tid == 0) {
      unsigned old = __hip_atomic_fetch_add(bar, 1u, __ATOMIC_RELAXED, __HIP_MEMORY_SCOPE_AGENT);
      if (old == (unsigned)(NCU * (t + 1) - 1)) {
        __hip_atomic_store(rel, (unsigned)(t + 1), __ATOMIC_RELAXED, __HIP_MEMORY_SCOPE_AGENT);
      } else {
        while (__hip_atomic_load(rel, __ATOMIC_RELAXED, __HIP_MEMORY_SCOPE_AGENT) < (unsigned)(t + 1)) {}
      }
    }
    __syncthreads();

    // ===== gate: read reduced proposed, update mem (replicated), write out slice =====
    {
      const u64* av = (const u64*)(accbuf + (size_t)(t & 3) * 4096);
      u64 vals[8];
#pragma unroll
      for (int q8 = 0; q8 < 8; q8++)
        vals[q8] = __hip_atomic_load(av + tid * 8 + q8, __ATOMIC_RELAXED, __HIP_MEMORY_SCOPE_AGENT);
      float nmv[16];
#pragma unroll
      for (int q8 = 0; q8 < 8; q8++) {
#pragma unroll
        for (int hlf = 0; hlf < 2; hlf++) {
          const int q = 2 * q8 + hlf;
          float v = __uint_as_float((unsigned)(hlf ? (vals[q8] >> 32) : vals[q8]));
          float prop = v + b2r[q];
          float g = 1.0f / (1.0f + __expf(-prop));
          float nm = memr[q] + g * (prop - memr[q]);
          memr[q] = nm;
          nmv[q] = nm;
        }
      }
      s16x8 vh0, vl0, vh1, vl1;
#pragma unroll
      for (int q = 0; q < 8; q++) {
        short hi = f2bf(nmv[q]);
        vh0[q] = hi; vl0[q] = f2bf(nmv[q] - bf2f(hi));
        short hi2 = f2bf(nmv[q + 8]);
        vh1[q] = hi2; vl1[q] = f2bf(nmv[q + 8] - bf2f(hi2));
      }
      *(s16x8*)(memh + mg * 520 + i0own) = vh0;
      *(s16x8*)(memh + mg * 520 + i0own + 8) = vh1;
      *(s16x8*)(meml + mg * 520 + i0own) = vl0;
      *(s16x8*)(meml + mg * 520 + i0own + 8) = vl1;
      if ((tid & 31) == c) {
        float* op = out + ((size_t)mg * TSTEPS + t) * 512 + i0own;
#pragma unroll
        for (int q4 = 0; q4 < 4; q4++) {
          f32x4 v;
#pragma unroll
          for (int j = 0; j < 4; j++) v[j] = nmv[q4 * 4 + j];
          *(f32x4*)(op + q4 * 4) = v;
        }
      }
    }
    __syncthreads();   // mem splits visible before next step's phase 1
  }
}

extern "C" void kernel_launch(void* const* d_in, const int* in_sizes, int n_in,
                              void* d_out, int out_size, void* d_ws, size_t ws_size,
                              hipStream_t stream) {
  const float* x  = (const float*)d_in[0];
  const float* W1 = (const float*)d_in[1];
  const float* b1 = (const float*)d_in[2];
  const float* W2 = (const float*)d_in[3];
  const float* b2 = (const float*)d_in[4];
  float* out = (float*)d_out;
  char* ws = (char*)d_ws;

  // workspace layout
  float*    accbuf = (float*)(ws + 0);          // 4 x 4096 f32 = 65,536 B
  unsigned* bar    = (unsigned*)(ws + 65536);
  unsigned* rel    = (unsigned*)(ws + 65664);
  float*    pre1   = (float*)(ws + (1u << 20)); // 4096*8*1024*4 = 134,217,728 B

  hipMemsetAsync(ws, 0, 65792, stream);         // zero acc buffers + bar + rel

  dim3 gp(256, 8);
  pre_gemm<<<gp, dim3(256), 0, stream>>>(x, W1, b1, pre1);

  const int LDS_BYTES = 162496;
  hipFuncSetAttribute((const void*)seq_scan,
                      hipFuncAttributeMaxDynamicSharedMemorySize, LDS_BYTES);
  seq_scan<<<dim3(NCU), dim3(256), LDS_BYTES, stream>>>(
      W1, W2, b2, pre1, out, accbuf, bar, rel);
}